// Round 4
// baseline (217.402 us; speedup 1.0000x reference)
//
#include <hip/hip_runtime.h>
#include <hip/hip_bf16.h>

typedef __attribute__((ext_vector_type(4))) short short4v;
typedef __attribute__((ext_vector_type(8))) short short8v;
typedef __attribute__((ext_vector_type(4))) float floatx4;

#define B_ROWS 2048
#define K_DIM  1024
#define N_CON  64
#define TWO_E  256
#define E_DIM  128
#define BM     64
#define BK     64
#define A_STRIDE 72   // padded LDS row (bf16 elems): 2-way bank aliasing only (free)
#define B_STRIDE 72
#define LDSA_BYTES (BM * A_STRIDE * 2)        // 9216
#define LDSB_BYTES (TWO_E * B_STRIDE * 2)     // 36864
#define SMEM_BYTES (LDSA_BYTES + LDSB_BYTES)  // 46080
#define EMB_ELEMS 16777216ULL                 // 2048*64*128

// fp32 -> bf16 bit pattern via the proven __float2bfloat16 + memcpy punning.
static __device__ inline unsigned short bf16bits(float f) {
    __hip_bfloat16 h = __float2bfloat16(f);
    unsigned short u;
    __builtin_memcpy(&u, &h, 2);
    return u;
}

// ---------------------------------------------------------------------------
// One-shot W transpose+convert: W[n][k][o] fp32 (o contiguous)
//   -> Wt[n][o][k] bf16 (k contiguous) in d_ws.
// ---------------------------------------------------------------------------
__global__ void __launch_bounds__(256) transpose_w(const float* __restrict__ W,
                                                   unsigned short* __restrict__ Wt) {
    __shared__ unsigned short t[64 * 68];
    const int tid = threadIdx.x;
    const int ot = blockIdx.x, ktile = blockIdx.y, n = blockIdx.z;
    const float* src = W + ((size_t)n * K_DIM + (size_t)ktile * 64) * TWO_E + ot * 64;
    unsigned short* dst = Wt + ((size_t)n * TWO_E + (size_t)ot * 64) * K_DIM + ktile * 64;

#pragma unroll
    for (int it = 0; it < 4; ++it) {
        int r = it * 16 + (tid >> 4);     // k row within tile
        int c = (tid & 15) * 4;           // o col within tile
        floatx4 v = *(const floatx4*)&src[(size_t)r * TWO_E + c];
        short4v b;
        b[0] = (short)bf16bits(v[0]);
        b[1] = (short)bf16bits(v[1]);
        b[2] = (short)bf16bits(v[2]);
        b[3] = (short)bf16bits(v[3]);
        *(short4v*)&t[r * 68 + c] = b;
    }
    __syncthreads();
#pragma unroll
    for (int it = 0; it < 4; ++it) {
        int o = it * 16 + (tid >> 4);
        int k = (tid & 15) * 4;
        short4v v;
#pragma unroll
        for (int j = 0; j < 4; ++j) v[j] = (short)t[(k + j) * 68 + o];
        *(short4v*)&dst[(size_t)o * K_DIM + k] = v;
    }
}

// ---------------------------------------------------------------------------
// Fused kernel: one WG = (64-row block) x (concept n), all 256 output cols.
// Wave w owns cols [64w, 64w+64). acc[4][4] of 16x16 MFMA tiles.
// Inputs fp32; MFMA in bf16; epilogue + stores in fp32.
// ---------------------------------------------------------------------------
template <bool PRET>
__global__ void __launch_bounds__(256, 2)
concept_kernel(const float* __restrict__ x,
               const float* __restrict__ Wc,            // [n][k][o] fp32
               const unsigned short* __restrict__ Wt,   // [n][o][k] bf16 (PRET)
               const float* __restrict__ bc,
               const float* __restrict__ wp,
               const float* __restrict__ bp,
               float* __restrict__ out) {
    __shared__ __align__(16) char smem[SMEM_BYTES];
    unsigned short* ldsA = (unsigned short*)smem;
    unsigned short* ldsB = (unsigned short*)(smem + LDSA_BYTES);

    const int tid  = threadIdx.x;
    const int wave = tid >> 6;
    const int lane = tid & 63;
    const int lg   = lane >> 4;    // quad group 0..3
    const int l15  = lane & 15;
    const int rb = blockIdx.x;     // row block 0..31
    const int n  = blockIdx.y;     // concept 0..63

    const float* xg = x + (size_t)rb * BM * K_DIM;

    floatx4 acc[4][4];
#pragma unroll
    for (int mi = 0; mi < 4; ++mi)
#pragma unroll
        for (int oi = 0; oi < 4; ++oi) acc[mi][oi] = (floatx4){0.f, 0.f, 0.f, 0.f};

    for (int kt = 0; kt < K_DIM; kt += BK) {
        // ---- stage A: x tile 64 rows x 64 k, fp32 -> bf16 ----
#pragma unroll
        for (int it = 0; it < 4; ++it) {
            int q = it * 256 + tid;        // 1024 chunks of 4 floats
            int r = q >> 4, c = (q & 15) * 4;
            floatx4 v = *(const floatx4*)&xg[(size_t)r * K_DIM + kt + c];
            short4v b;
            b[0] = (short)bf16bits(v[0]);
            b[1] = (short)bf16bits(v[1]);
            b[2] = (short)bf16bits(v[2]);
            b[3] = (short)bf16bits(v[3]);
            *(short4v*)&ldsA[r * A_STRIDE + c] = b;
        }
        // ---- stage B: W tile -> lds[o][k] bf16 ----
        if (PRET) {
            const unsigned short* wtg = Wt + (size_t)n * TWO_E * K_DIM;
#pragma unroll
            for (int it = 0; it < 8; ++it) {
                int q = it * 256 + tid;    // 2048 chunks of 16B
                int o = q >> 3, ck = q & 7;
                short8v v = *(const short8v*)&wtg[(size_t)o * K_DIM + kt + ck * 8];
                *(short8v*)&ldsB[o * B_STRIDE + ck * 8] = v;
            }
        } else {
            const float* wg = Wc + (size_t)n * K_DIM * TWO_E;
#pragma unroll
            for (int it = 0; it < 8; ++it) {   // o = tid, k-octet = it
                short8v v;
#pragma unroll
                for (int j = 0; j < 8; ++j)
                    v[j] = (short)bf16bits(wg[(size_t)(kt + it * 8 + j) * TWO_E + tid]);
                *(short8v*)&ldsB[tid * B_STRIDE + it * 8] = v;
            }
        }
        __syncthreads();

#pragma unroll
        for (int ks = 0; ks < 2; ++ks) {
            const int kof = ks * 32 + lg * 8;
            short8v af[4], bfr[4];
#pragma unroll
            for (int mi = 0; mi < 4; ++mi)
                af[mi] = *(short8v*)&ldsA[(mi * 16 + l15) * A_STRIDE + kof];
#pragma unroll
            for (int oi = 0; oi < 4; ++oi)
                bfr[oi] = *(short8v*)&ldsB[(wave * 64 + oi * 16 + l15) * B_STRIDE + kof];
#pragma unroll
            for (int mi = 0; mi < 4; ++mi)
#pragma unroll
                for (int oi = 0; oi < 4; ++oi)
                    acc[mi][oi] = __builtin_amdgcn_mfma_f32_16x16x32_bf16(
                        af[mi], bfr[oi], acc[mi][oi], 0, 0, 0);
        }
        __syncthreads();
    }

    // ---- epilogue (fp32) ----
    float biasf[4], wpf[4];
#pragma unroll
    for (int oi = 0; oi < 4; ++oi) {
        int o = wave * 64 + oi * 16 + l15;
        biasf[oi] = bc[n * TWO_E + o];
        wpf[oi]  = wp[o];
    }
#pragma unroll
    for (int mi = 0; mi < 4; ++mi)
#pragma unroll
        for (int oi = 0; oi < 4; ++oi)
#pragma unroll
            for (int j = 0; j < 4; ++j) {
                float v = acc[mi][oi][j] + biasf[oi];
                acc[mi][oi][j] = v >= 0.f ? v : 0.01f * v;   // LeakyReLU
            }

    // reuse tile LDS (dead after last barrier) for epilogue scratch
    float* eneg    = (float*)smem;                 // [64][132] negative-half ctx
    float* partial = (float*)(smem + 33792);       // [64][4] per-wave row dots
    float* pv      = (float*)(smem + 34816);       // [64] gate probs

    if (wave >= 2) {   // stash negative half (o >= 128)
#pragma unroll
        for (int mi = 0; mi < 4; ++mi)
#pragma unroll
            for (int oi = 0; oi < 4; ++oi)
#pragma unroll
                for (int j = 0; j < 4; ++j) {
                    int row = mi * 16 + lg * 4 + j;
                    int e = (wave - 2) * 64 + oi * 16 + l15;
                    eneg[row * 132 + e] = acc[mi][oi][j];
                }
    }
    // per-wave partial row dots with w_prob
#pragma unroll
    for (int mi = 0; mi < 4; ++mi)
#pragma unroll
        for (int j = 0; j < 4; ++j) {
            float ps = 0.f;
#pragma unroll
            for (int oi = 0; oi < 4; ++oi) ps += acc[mi][oi][j] * wpf[oi];
            ps += __shfl_xor(ps, 1);
            ps += __shfl_xor(ps, 2);
            ps += __shfl_xor(ps, 4);
            ps += __shfl_xor(ps, 8);
            if (l15 == 0) partial[(mi * 16 + lg * 4 + j) * 4 + wave] = ps;
        }
    __syncthreads();

    if (tid < 64) {
        float s = partial[tid * 4] + partial[tid * 4 + 1] + partial[tid * 4 + 2] +
                  partial[tid * 4 + 3] + bp[0];
        float p = 1.f / (1.f + __expf(-s));
        pv[tid] = p;
        size_t bi = (size_t)rb * BM + tid;
        out[EMB_ELEMS + bi * N_CON + n] = p;    // c_pred (fp32)
    }
    __syncthreads();

    if (wave < 2) {    // blend + store c_emb (fp32)
#pragma unroll
        for (int mi = 0; mi < 4; ++mi)
#pragma unroll
            for (int oi = 0; oi < 4; ++oi)
#pragma unroll
                for (int j = 0; j < 4; ++j) {
                    int row = mi * 16 + lg * 4 + j;
                    int e = wave * 64 + oi * 16 + l15;
                    float p = pv[row];
                    float v = acc[mi][oi][j] * p + eneg[row * 132 + e] * (1.f - p);
                    size_t bi = (size_t)rb * BM + row;
                    out[(bi * N_CON + n) * E_DIM + e] = v;
                }
    }
}

extern "C" void kernel_launch(void* const* d_in, const int* in_sizes, int n_in,
                              void* d_out, int out_size, void* d_ws, size_t ws_size,
                              hipStream_t stream) {
    const float* x  = (const float*)d_in[0];
    const float* Wc = (const float*)d_in[1];
    const float* bc = (const float*)d_in[2];
    const float* wp = (const float*)d_in[3];
    const float* bp = (const float*)d_in[4];
    float* out = (float*)d_out;

    const size_t wt_bytes = (size_t)N_CON * K_DIM * TWO_E * 2;  // 33.5 MB bf16
    if (ws_size >= wt_bytes) {
        unsigned short* Wt = (unsigned short*)d_ws;
        transpose_w<<<dim3(4, 16, 64), 256, 0, stream>>>(Wc, Wt);
        concept_kernel<true><<<dim3(32, 64), 256, 0, stream>>>(x, Wc, Wt, bc, wp, bp, out);
    } else {
        concept_kernel<false><<<dim3(32, 64), 256, 0, stream>>>(x, Wc, nullptr, bc, wp, bp, out);
    }
}

// Round 5
// 205.328 us; speedup vs baseline: 1.0588x; 1.0588x over previous
//
#include <hip/hip_runtime.h>
#include <hip/hip_bf16.h>

typedef __attribute__((ext_vector_type(4))) short short4v;
typedef __attribute__((ext_vector_type(8))) short short8v;
typedef __attribute__((ext_vector_type(4))) float floatx4;

#define B_ROWS 2048
#define K_DIM  1024
#define N_CON  64
#define TWO_E  256
#define E_DIM  128
#define BM     128
#define BK     64
#define A_STRIDE 72   // padded LDS row (bf16 elems)
#define B_STRIDE 72
#define LDSA_BYTES (BM * A_STRIDE * 2)        // 18432
#define LDSB_BYTES (TWO_E * B_STRIDE * 2)     // 36864
#define SMEM_BYTES (LDSA_BYTES + LDSB_BYTES)  // 55296
#define EMB_ELEMS 16777216ULL                 // 2048*64*128

// fp32 -> bf16 bit pattern via proven __float2bfloat16 + memcpy punning.
static __device__ inline unsigned short bf16bits(float f) {
    __hip_bfloat16 h = __float2bfloat16(f);
    unsigned short u;
    __builtin_memcpy(&u, &h, 2);
    return u;
}

// ---------------------------------------------------------------------------
// W transpose+convert: W[n][k][o] fp32 -> Wt[n][o][k] bf16.
// k/k+1 bf16 pairs packed into LDS dwords => phase 2 is ds_read_b128 +
// 16-B global store (k-contiguous), both phases fully vectorized.
// Tile: 64k x 64o. Grid (ot=4, ktile=16, n=64).
// ---------------------------------------------------------------------------
__global__ void __launch_bounds__(256) transpose_w(const float* __restrict__ W,
                                                   unsigned short* __restrict__ Wt) {
    __shared__ unsigned int lds2[64 * 36];   // [o][kpair], 36-dword rows (16B-aligned, pad)
    const int tid = threadIdx.x;
    const int ot = blockIdx.x, ktile = blockIdx.y, n = blockIdx.z;
    const float* src = W + ((size_t)n * K_DIM + (size_t)ktile * 64) * TWO_E + ot * 64;
    unsigned short* dst = Wt + ((size_t)n * TWO_E + (size_t)ot * 64) * K_DIM + ktile * 64;

    const int kp = tid >> 4;          // pair id 0..15 (per iter)
    const int c  = (tid & 15) * 4;    // o base 0..60
#pragma unroll
    for (int it = 0; it < 2; ++it) {
        const int k0 = it * 32 + kp * 2;
        floatx4 r0 = *(const floatx4*)&src[(size_t)k0 * TWO_E + c];
        floatx4 r1 = *(const floatx4*)&src[(size_t)(k0 + 1) * TWO_E + c];
#pragma unroll
        for (int j = 0; j < 4; ++j) {
            unsigned int d = (unsigned int)bf16bits(r0[j]) |
                             ((unsigned int)bf16bits(r1[j]) << 16);
            lds2[(c + j) * 36 + it * 16 + kp] = d;   // [o][kpair]
        }
    }
    __syncthreads();
#pragma unroll
    for (int it = 0; it < 2; ++it) {
        int q = it * 256 + tid;       // 512 chunks of 16B
        int o = q >> 3, kc = q & 7;
        short8v v = *(short8v*)&lds2[o * 36 + kc * 4];   // 8 consecutive k at fixed o
        *(short8v*)&dst[(size_t)o * K_DIM + kc * 8] = v;
    }
}

// ---------------------------------------------------------------------------
// Fused GEMM: one WG = (128-row block rb) x (concept n), 512 thr / 8 waves.
// Wave w: row-half h=w>>2 (64 rows), o-group og=w&3 owning o-tiles
// {og*32, og*32+16, og*32+128, og*32+144} -> pos & neg halves in-lane,
// blend is in-register (no eneg LDS round-trip).
// ---------------------------------------------------------------------------
template <bool PRET>
__global__ void __launch_bounds__(512, 4)
concept_kernel(const float* __restrict__ x,
               const float* __restrict__ Wc,            // [n][k][o] fp32 (fallback)
               const unsigned short* __restrict__ Wt,   // [n][o][k] bf16 (PRET)
               const float* __restrict__ bc,
               const float* __restrict__ wp,
               const float* __restrict__ bp,
               float* __restrict__ out) {
    __shared__ __align__(16) char smem[SMEM_BYTES];
    unsigned short* ldsA = (unsigned short*)smem;
    unsigned short* ldsB = (unsigned short*)(smem + LDSA_BYTES);

    const int tid  = threadIdx.x;
    const int wave = tid >> 6;
    const int lane = tid & 63;
    const int lg   = lane >> 4;       // quad group 0..3
    const int l15  = lane & 15;
    const int h    = wave >> 2;       // row half 0..1
    const int og   = wave & 3;        // o group 0..3
    const int rb = blockIdx.x;        // row block 0..15
    const int n  = blockIdx.y;        // concept 0..63

    int otile[4];
#pragma unroll
    for (int oi = 0; oi < 4; ++oi) otile[oi] = og * 32 + (oi & 1) * 16 + (oi & 2) * 64;

    const float* xg = x + (size_t)rb * BM * K_DIM;

    floatx4 acc[4][4];
#pragma unroll
    for (int mi = 0; mi < 4; ++mi)
#pragma unroll
        for (int oi = 0; oi < 4; ++oi) acc[mi][oi] = (floatx4){0.f, 0.f, 0.f, 0.f};

    for (int kt = 0; kt < K_DIM; kt += BK) {
        // ---- stage A: x tile 128 rows x 64 k, fp32 -> bf16 ----
#pragma unroll
        for (int it = 0; it < 4; ++it) {
            int q = it * 512 + tid;        // 2048 chunks of 4 floats
            int r = q >> 4, c = (q & 15) * 4;
            floatx4 v = *(const floatx4*)&xg[(size_t)r * K_DIM + kt + c];
            short4v b;
            b[0] = (short)bf16bits(v[0]);
            b[1] = (short)bf16bits(v[1]);
            b[2] = (short)bf16bits(v[2]);
            b[3] = (short)bf16bits(v[3]);
            *(short4v*)&ldsA[r * A_STRIDE + c] = b;
        }
        // ---- stage B: Wt tile 256 o x 64 k bf16 ----
        if (PRET) {
            const unsigned short* wtg = Wt + (size_t)n * TWO_E * K_DIM;
#pragma unroll
            for (int it = 0; it < 4; ++it) {
                int q = it * 512 + tid;    // 2048 chunks of 16B
                int o = q >> 3, ck = q & 7;
                short8v v = *(const short8v*)&wtg[(size_t)o * K_DIM + kt + ck * 8];
                *(short8v*)&ldsB[o * B_STRIDE + ck * 8] = v;
            }
        } else {
            if (tid < 256) {
                const float* wg = Wc + (size_t)n * K_DIM * TWO_E;
#pragma unroll
                for (int it = 0; it < 8; ++it) {
                    short8v v;
#pragma unroll
                    for (int j = 0; j < 8; ++j)
                        v[j] = (short)bf16bits(wg[(size_t)(kt + it * 8 + j) * TWO_E + tid]);
                    *(short8v*)&ldsB[tid * B_STRIDE + it * 8] = v;
                }
            }
        }
        __syncthreads();

#pragma unroll
        for (int ks = 0; ks < 2; ++ks) {
            const int kof = ks * 32 + lg * 8;
            short8v af[4], bfr[4];
#pragma unroll
            for (int mi = 0; mi < 4; ++mi)
                af[mi] = *(short8v*)&ldsA[(h * 64 + mi * 16 + l15) * A_STRIDE + kof];
#pragma unroll
            for (int oi = 0; oi < 4; ++oi)
                bfr[oi] = *(short8v*)&ldsB[(otile[oi] + l15) * B_STRIDE + kof];
#pragma unroll
            for (int mi = 0; mi < 4; ++mi)
#pragma unroll
                for (int oi = 0; oi < 4; ++oi)
                    acc[mi][oi] = __builtin_amdgcn_mfma_f32_16x16x32_bf16(
                        af[mi], bfr[oi], acc[mi][oi], 0, 0, 0);
        }
        __syncthreads();
    }

    // ---- epilogue (fp32) ----
    float biasf[4], wpf[4];
#pragma unroll
    for (int oi = 0; oi < 4; ++oi) {
        int o = otile[oi] + l15;
        biasf[oi] = bc[n * TWO_E + o];
        wpf[oi]  = wp[o];
    }
#pragma unroll
    for (int mi = 0; mi < 4; ++mi)
#pragma unroll
        for (int oi = 0; oi < 4; ++oi)
#pragma unroll
            for (int j = 0; j < 4; ++j) {
                float v = acc[mi][oi][j] + biasf[oi];
                acc[mi][oi][j] = v >= 0.f ? v : 0.01f * v;   // LeakyReLU
            }

    // reuse tile LDS (dead after final barrier) for gate scratch
    float* partial = (float*)smem;            // [128][4] per-og row dots
    float* pv      = (float*)(smem + 2048);   // [128] gate probs

    // per-wave partial row dots with w_prob (covers this wave's 8 o-16-tiles? no:
    // its 4 tiles; og groups tile o-space disjointly, union = all 256 cols)
#pragma unroll
    for (int mi = 0; mi < 4; ++mi)
#pragma unroll
        for (int j = 0; j < 4; ++j) {
            float ps = 0.f;
#pragma unroll
            for (int oi = 0; oi < 4; ++oi) ps += acc[mi][oi][j] * wpf[oi];
            ps += __shfl_xor(ps, 1);
            ps += __shfl_xor(ps, 2);
            ps += __shfl_xor(ps, 4);
            ps += __shfl_xor(ps, 8);
            if (l15 == 0) partial[(h * 64 + mi * 16 + lg * 4 + j) * 4 + og] = ps;
        }
    __syncthreads();

    if (tid < 128) {
        float s = partial[tid * 4] + partial[tid * 4 + 1] + partial[tid * 4 + 2] +
                  partial[tid * 4 + 3] + bp[0];
        float p = 1.f / (1.f + __expf(-s));
        pv[tid] = p;
        size_t bi = (size_t)rb * BM + tid;
        out[EMB_ELEMS + bi * N_CON + n] = p;    // c_pred
    }
    __syncthreads();

    // blend in-register: pos tiles oi 0..1 pair with neg tiles oi+2
#pragma unroll
    for (int mi = 0; mi < 4; ++mi)
#pragma unroll
        for (int oi = 0; oi < 2; ++oi)
#pragma unroll
            for (int j = 0; j < 4; ++j) {
                int row = h * 64 + mi * 16 + lg * 4 + j;
                int e = og * 32 + oi * 16 + l15;
                float p = pv[row];
                float v = acc[mi][oi][j] * p + acc[mi][oi + 2][j] * (1.f - p);
                size_t bi = (size_t)rb * BM + row;
                out[(bi * N_CON + n) * E_DIM + e] = v;
            }
}

extern "C" void kernel_launch(void* const* d_in, const int* in_sizes, int n_in,
                              void* d_out, int out_size, void* d_ws, size_t ws_size,
                              hipStream_t stream) {
    const float* x  = (const float*)d_in[0];
    const float* Wc = (const float*)d_in[1];
    const float* bc = (const float*)d_in[2];
    const float* wp = (const float*)d_in[3];
    const float* bp = (const float*)d_in[4];
    float* out = (float*)d_out;

    const size_t wt_bytes = (size_t)N_CON * K_DIM * TWO_E * 2;  // 33.5 MB bf16
    if (ws_size >= wt_bytes) {
        unsigned short* Wt = (unsigned short*)d_ws;
        transpose_w<<<dim3(4, 16, 64), 256, 0, stream>>>(Wc, Wt);
        concept_kernel<true><<<dim3(16, 64), 512, 0, stream>>>(x, Wc, Wt, bc, wp, bp, out);
    } else {
        concept_kernel<false><<<dim3(16, 64), 512, 0, stream>>>(x, Wc, nullptr, bc, wp, bp, out);
    }
}

// Round 6
// 189.488 us; speedup vs baseline: 1.1473x; 1.0836x over previous
//
#include <hip/hip_runtime.h>
#include <hip/hip_bf16.h>

typedef __attribute__((ext_vector_type(4))) short short4v;
typedef __attribute__((ext_vector_type(8))) short short8v;
typedef __attribute__((ext_vector_type(4))) float floatx4;

#define B_ROWS 2048
#define K_DIM  1024
#define N_CON  64
#define TWO_E  256
#define E_DIM  128
#define BM     128
#define BK     64
#define LDSA_BYTES (BM * BK * 2)              // 16384, 128B rows, swizzled
#define LDSB_BYTES (TWO_E * BK * 2)           // 32768
#define SMEM_BYTES (LDSA_BYTES + LDSB_BYTES)  // 49152
#define EMB_ELEMS 16777216ULL                 // 2048*64*128
#define WT_BYTES  33554432ULL                 // 64*256*1024*2
#define XB_BYTES  4194304ULL                  // 2048*1024*2

// fp32 -> bf16 bit pattern via proven __float2bfloat16 + memcpy punning.
static __device__ inline unsigned short bf16bits(float f) {
    __hip_bfloat16 h = __float2bfloat16(f);
    unsigned short u;
    __builtin_memcpy(&u, &h, 2);
    return u;
}

// Async 16B global->LDS DMA. LDS dest = wave-uniform base + lane*16 (m104).
static __device__ inline void dma16(const void* g, void* l) {
    __builtin_amdgcn_global_load_lds(
        (const __attribute__((address_space(1))) unsigned int*)g,
        (__attribute__((address_space(3))) unsigned int*)l,
        16, 0, 0);
}

// ---------------------------------------------------------------------------
// Pre-pass: (a) W[n][k][o] fp32 -> Wt[n][o][k] bf16 (k-pair dword packing in
// LDS so both phases are fully vectorized); (b) x fp32 -> xb bf16.
// Grid (4,16,64).
// ---------------------------------------------------------------------------
__global__ void __launch_bounds__(256) prep(const float* __restrict__ W,
                                            const float* __restrict__ x,
                                            unsigned short* __restrict__ Wt,
                                            unsigned short* __restrict__ xb) {
    __shared__ unsigned int lds2[64 * 36];   // [o][kpair], padded rows
    const int tid = threadIdx.x;
    const int ot = blockIdx.x, ktile = blockIdx.y, n = blockIdx.z;
    const float* src = W + ((size_t)n * K_DIM + (size_t)ktile * 64) * TWO_E + ot * 64;
    unsigned short* dst = Wt + ((size_t)n * TWO_E + (size_t)ot * 64) * K_DIM + ktile * 64;

    const int kp = tid >> 4;          // pair id 0..15 per iter
    const int c  = (tid & 15) * 4;    // o base
#pragma unroll
    for (int it = 0; it < 2; ++it) {
        const int k0 = it * 32 + kp * 2;
        floatx4 r0 = *(const floatx4*)&src[(size_t)k0 * TWO_E + c];
        floatx4 r1 = *(const floatx4*)&src[(size_t)(k0 + 1) * TWO_E + c];
#pragma unroll
        for (int j = 0; j < 4; ++j) {
            unsigned int d = (unsigned int)bf16bits(r0[j]) |
                             ((unsigned int)bf16bits(r1[j]) << 16);
            lds2[(c + j) * 36 + it * 16 + kp] = d;
        }
    }
    __syncthreads();
#pragma unroll
    for (int it = 0; it < 2; ++it) {
        int q = it * 256 + tid;
        int o = q >> 3, kc = q & 7;
        short8v v = *(short8v*)&lds2[o * 36 + kc * 4];
        *(short8v*)&dst[(size_t)o * K_DIM + kc * 8] = v;
    }

    // ---- x convert: 2M elems over 4096 blocks, 2 per thread ----
    const int bid = blockIdx.x + blockIdx.y * 4 + blockIdx.z * 64;
    const size_t base = (size_t)bid * 512 + (size_t)tid * 2;
    unsigned int d = (unsigned int)bf16bits(x[base]) |
                     ((unsigned int)bf16bits(x[base + 1]) << 16);
    ((unsigned int*)xb)[base >> 1] = d;
}

// ---------------------------------------------------------------------------
// Fused GEMM. One WG = (128-row block rb) x (concept n), 512 thr / 8 waves.
// Wave: row-half h = w>>2, o-group og = w&3 with o-tiles
// {og*32, og*32+16, og*32+128, og*32+144} -> in-register pos/neg blend.
// PRET: bf16 operands staged via global_load_lds into XOR-swizzled LDS
// (slot granule = data granule ^ (row&7), 16B granules, 128B rows).
// ---------------------------------------------------------------------------
template <bool PRET>
__global__ void __launch_bounds__(512, 4)
concept_kernel(const float* __restrict__ x,
               const unsigned short* __restrict__ xb,   // bf16 (PRET)
               const float* __restrict__ Wc,            // fp32 (fallback)
               const unsigned short* __restrict__ Wt,   // bf16 [n][o][k] (PRET)
               const float* __restrict__ bc,
               const float* __restrict__ wp,
               const float* __restrict__ bp,
               float* __restrict__ out) {
    __shared__ __align__(16) char smem[SMEM_BYTES];
    char* ldsA = smem;
    char* ldsB = smem + LDSA_BYTES;

    const int tid  = threadIdx.x;
    const int wave = tid >> 6;
    const int lane = tid & 63;
    const int lg   = lane >> 4;       // quad 0..3
    const int l15  = lane & 15;
    const int h    = wave >> 2;       // row half
    const int og   = wave & 3;        // o group
    const int rb = blockIdx.x;        // 0..15
    const int n  = blockIdx.y;        // 0..63

    int otile[4];
#pragma unroll
    for (int oi = 0; oi < 4; ++oi) otile[oi] = og * 32 + (oi & 1) * 16 + (oi & 2) * 64;

    floatx4 acc[4][4];
#pragma unroll
    for (int mi = 0; mi < 4; ++mi)
#pragma unroll
        for (int oi = 0; oi < 4; ++oi) acc[mi][oi] = (floatx4){0.f, 0.f, 0.f, 0.f};

    const unsigned short* xrow  = PRET ? xb + (size_t)rb * BM * K_DIM : nullptr;
    const unsigned short* wbase = PRET ? Wt + (size_t)n * TWO_E * K_DIM : nullptr;
    const float* xg = x + (size_t)rb * BM * K_DIM;
    const float* wg = Wc + (size_t)n * K_DIM * TWO_E;

    for (int kt = 0; kt < K_DIM; kt += BK) {
        if (PRET) {
            // ---- A: 1024 granules (16KB), 8 waves x 2 iters ----
#pragma unroll
            for (int it = 0; it < 2; ++it) {
                int c = it * 8 + wave;
                int s = c * 64 + lane;
                int r = s >> 3, g = s & 7;
                dma16(xrow + (size_t)r * K_DIM + kt + ((g ^ (r & 7)) * 8),
                      ldsA + c * 1024);
            }
            // ---- B: 2048 granules (32KB), 8 waves x 4 iters ----
#pragma unroll
            for (int it = 0; it < 4; ++it) {
                int c = it * 8 + wave;
                int s = c * 64 + lane;
                int r = s >> 3, g = s & 7;
                dma16(wbase + (size_t)r * K_DIM + kt + ((g ^ (r & 7)) * 8),
                      ldsB + c * 1024);
            }
        } else {
            // manual staging into the same swizzled layout
#pragma unroll
            for (int it = 0; it < 2; ++it) {            // A: 2 granules/thread
                int s = it * 512 + tid;
                int r = s >> 3, g = s & 7;
                const float* p = xg + (size_t)r * K_DIM + kt + ((g ^ (r & 7)) * 8);
                floatx4 v0 = *(const floatx4*)p, v1 = *(const floatx4*)(p + 4);
                short8v b;
                b[0] = (short)bf16bits(v0[0]); b[1] = (short)bf16bits(v0[1]);
                b[2] = (short)bf16bits(v0[2]); b[3] = (short)bf16bits(v0[3]);
                b[4] = (short)bf16bits(v1[0]); b[5] = (short)bf16bits(v1[1]);
                b[6] = (short)bf16bits(v1[2]); b[7] = (short)bf16bits(v1[3]);
                *(short8v*)(ldsA + s * 16) = b;
            }
#pragma unroll
            for (int it = 0; it < 4; ++it) {            // B: 4 granules/thread
                int s = it * 512 + tid;
                int r = s >> 3, g = s & 7;
                int k0 = kt + (g ^ (r & 7)) * 8;
                short8v b;
#pragma unroll
                for (int j = 0; j < 8; ++j)
                    b[j] = (short)bf16bits(wg[(size_t)(k0 + j) * TWO_E + r]);
                *(short8v*)(ldsB + s * 16) = b;
            }
        }
        __syncthreads();

#pragma unroll
        for (int ks = 0; ks < 2; ++ks) {
            const int sw = ((ks * 4 + lg) ^ (l15 & 7)) * 16;
            short8v af[4], bfr[4];
#pragma unroll
            for (int mi = 0; mi < 4; ++mi)
                af[mi] = *(const short8v*)(ldsA + (h * 64 + mi * 16 + l15) * 128 + sw);
#pragma unroll
            for (int oi = 0; oi < 4; ++oi)
                bfr[oi] = *(const short8v*)(ldsB + (otile[oi] + l15) * 128 + sw);
#pragma unroll
            for (int mi = 0; mi < 4; ++mi)
#pragma unroll
                for (int oi = 0; oi < 4; ++oi)
                    acc[mi][oi] = __builtin_amdgcn_mfma_f32_16x16x32_bf16(
                        af[mi], bfr[oi], acc[mi][oi], 0, 0, 0);
        }
        __syncthreads();
    }

    // ---- epilogue (fp32) ----
    float biasf[4], wpf[4];
#pragma unroll
    for (int oi = 0; oi < 4; ++oi) {
        int o = otile[oi] + l15;
        biasf[oi] = bc[n * TWO_E + o];
        wpf[oi]  = wp[o];
    }
#pragma unroll
    for (int mi = 0; mi < 4; ++mi)
#pragma unroll
        for (int oi = 0; oi < 4; ++oi)
#pragma unroll
            for (int j = 0; j < 4; ++j) {
                float v = acc[mi][oi][j] + biasf[oi];
                acc[mi][oi][j] = v >= 0.f ? v : 0.01f * v;   // LeakyReLU
            }

    float* partial = (float*)smem;            // [128][4]
    float* pv      = (float*)(smem + 2048);   // [128]

#pragma unroll
    for (int mi = 0; mi < 4; ++mi)
#pragma unroll
        for (int j = 0; j < 4; ++j) {
            float ps = 0.f;
#pragma unroll
            for (int oi = 0; oi < 4; ++oi) ps += acc[mi][oi][j] * wpf[oi];
            ps += __shfl_xor(ps, 1);
            ps += __shfl_xor(ps, 2);
            ps += __shfl_xor(ps, 4);
            ps += __shfl_xor(ps, 8);
            if (l15 == 0) partial[(h * 64 + mi * 16 + lg * 4 + j) * 4 + og] = ps;
        }
    __syncthreads();

    if (tid < 128) {
        float s = partial[tid * 4] + partial[tid * 4 + 1] + partial[tid * 4 + 2] +
                  partial[tid * 4 + 3] + bp[0];
        float p = 1.f / (1.f + __expf(-s));
        pv[tid] = p;
        size_t bi = (size_t)rb * BM + tid;
        out[EMB_ELEMS + bi * N_CON + n] = p;    // c_pred
    }
    __syncthreads();

#pragma unroll
    for (int mi = 0; mi < 4; ++mi)
#pragma unroll
        for (int oi = 0; oi < 2; ++oi)
#pragma unroll
            for (int j = 0; j < 4; ++j) {
                int row = h * 64 + mi * 16 + lg * 4 + j;
                int e = og * 32 + oi * 16 + l15;
                float p = pv[row];
                float v = acc[mi][oi][j] * p + acc[mi][oi + 2][j] * (1.f - p);
                size_t bi = (size_t)rb * BM + row;
                out[(bi * N_CON + n) * E_DIM + e] = v;
            }
}

extern "C" void kernel_launch(void* const* d_in, const int* in_sizes, int n_in,
                              void* d_out, int out_size, void* d_ws, size_t ws_size,
                              hipStream_t stream) {
    const float* x  = (const float*)d_in[0];
    const float* Wc = (const float*)d_in[1];
    const float* bc = (const float*)d_in[2];
    const float* wp = (const float*)d_in[3];
    const float* bp = (const float*)d_in[4];
    float* out = (float*)d_out;

    if (ws_size >= WT_BYTES + XB_BYTES) {
        unsigned short* Wt = (unsigned short*)d_ws;
        unsigned short* xb = (unsigned short*)((char*)d_ws + WT_BYTES);
        prep<<<dim3(4, 16, 64), 256, 0, stream>>>(Wc, x, Wt, xb);
        concept_kernel<true><<<dim3(16, 64), 512, 0, stream>>>(
            x, xb, Wc, Wt, bc, wp, bp, out);
    } else {
        concept_kernel<false><<<dim3(16, 64), 512, 0, stream>>>(
            x, nullptr, Wc, nullptr, bc, wp, bp, out);
    }
}